// Round 15
// baseline (222.535 us; speedup 1.0000x reference)
//
#include <hip/hip_runtime.h>
#include <math.h>

typedef __attribute__((ext_vector_type(8))) short  bf16x8;
typedef __attribute__((ext_vector_type(8))) unsigned short u16x8;
typedef __attribute__((ext_vector_type(4))) float  f32x4;

#define MTOT 16384   // B*H*W

__device__ __forceinline__ float b2f(unsigned short h) {
  return __uint_as_float(((unsigned int)h) << 16);
}
__device__ __forceinline__ unsigned short f2bf(float f) {
  unsigned int u = __float_as_uint(f);
  unsigned int r = (u + 0x7fffu + ((u >> 16) & 1u)) >> 16;
  return (unsigned short)r;
}
__device__ __forceinline__ void gload16(const unsigned short* g, unsigned short* l) {
  __builtin_amdgcn_global_load_lds(
      (const __attribute__((address_space(1))) void*)g,
      (__attribute__((address_space(3))) void*)l, 16, 0, 0);
}

// ------- NCHW fp32 -> chunked bf16 planes  out[c4][m][64]  (m = b*4096 + y*64 + x) -------
__global__ __launch_bounds__(256) void nhwc_kernel(const float* __restrict__ in,
                                                   unsigned short* __restrict__ out) {
  const int y = blockIdx.x, b = blockIdx.y;
  const int t = threadIdx.x;
  __shared__ float lds[64 * 65];
  for (int c0 = 0; c0 < 256; c0 += 64) {
    #pragma unroll
    for (int i = 0; i < 16; ++i) {
      int cl = i * 4 + (t >> 6);
      int xx = t & 63;
      lds[cl * 65 + xx] = in[(((size_t)b * 256 + c0 + cl) * 64 + y) * 64 + xx];
    }
    __syncthreads();
    const int plane = c0 >> 6;
    #pragma unroll
    for (int i = 0; i < 16; ++i) {
      int xx = i * 4 + (t >> 6);
      int cl = t & 63;
      int m  = (b << 12) + (y << 6) + xx;
      out[((size_t)plane * MTOT + m) * 64 + cl] = f2bf(lds[cl * 65 + xx]);
    }
    __syncthreads();
  }
}

// ------- weight reorder: w[co][ci][kk] fp32 -> Wp[(kk*4+c4)*NPAD + co][64ci] bf16 -------
__global__ __launch_bounds__(256) void wprep_kernel(const float* __restrict__ w,
                                                    unsigned short* __restrict__ Wp,
                                                    int NPAD, int COUT_valid) {
  const int kkc4 = blockIdx.x;             // 0..35
  const int kk = kkc4 >> 2, c4 = kkc4 & 3;
  const int co = blockIdx.y * 4 + (threadIdx.x >> 6);
  const int c16 = threadIdx.x & 63;
  float v = (co < COUT_valid) ? w[((size_t)co * 256 + c4 * 64 + c16) * 9 + kk] : 0.0f;
  Wp[((size_t)kkc4 * NPAD + co) * 64 + c16] = f2bf(v);
}

// ========== 8-wave (512-thr) MFMA GEMM, 128x128 tile, wave tile 64x32 ==========
// (unchanged from R14 — proven) EPI: 0 = silu -> bf16 chunked planes; 1 = f32 [m][432]+bias.
template<int NPAD, int EPI, bool IMPLICIT>
__global__ __launch_bounds__(512, 1) void gemm8_kernel(
    const unsigned short* __restrict__ A,
    const unsigned short* __restrict__ W,
    const float* __restrict__ bias,
    void* __restrict__ outp,
    const unsigned short* __restrict__ zbuf,
    int Nvalid) {
  constexpr int BM = 128, BN = 128, BK = 64;
  constexpr int NSTEP = 36;
  constexpr int BUFE = (BM + BN) * BK;            // 32 KB
  __shared__ unsigned short lds[2][BUFE];

  const int t = threadIdx.x, lane = t & 63, w = t >> 6;   // w: 0..7
  const int wm = w >> 2, wn = w & 3;
  const int m0 = blockIdx.x * BM, n0 = blockIdx.y * BN;

  const unsigned short* baseA[2];
  const unsigned short* zsrcA[2];
  unsigned int vmaskA[2];
  #pragma unroll
  for (int i = 0; i < 2; ++i) {
    int c   = (i * 8 + w) * 64 + lane;
    int row = c >> 3;
    int ccl = (c & 7) ^ (row & 7);
    int m   = m0 + row;
    baseA[i] = A + (size_t)m * 64 + ccl * 8;
    zsrcA[i] = zbuf + ccl * 8;
    if (IMPLICIT) {
      int y = (m >> 6) & 63, x = m & 63;
      unsigned int vm = 0;
      #pragma unroll
      for (int kk = 0; kk < 9; ++kk) {
        int dy = kk / 3 - 1, dx = kk % 3 - 1;
        if ((unsigned)(y + dy) < 64u && (unsigned)(x + dx) < 64u) vm |= (1u << kk);
      }
      vmaskA[i] = vm;
    } else {
      vmaskA[i] = 0;
    }
  }
  const unsigned short* baseB[2];
  #pragma unroll
  for (int j = 0; j < 2; ++j) {
    int c   = (j * 8 + w) * 64 + lane;
    int row = c >> 3;
    int ccl = (c & 7) ^ (row & 7);
    baseB[j] = W + (size_t)(n0 + row) * 64 + ccl * 8;
  }

  int offA[4][2], offB[2][2];
  #pragma unroll
  for (int mi = 0; mi < 4; ++mi) {
    int r = wm * 64 + mi * 16 + (lane & 15);
    #pragma unroll
    for (int kh = 0; kh < 2; ++kh) {
      int ccl = kh * 4 + (lane >> 4);
      offA[mi][kh] = r * 64 + ((ccl ^ (r & 7)) * 8);
    }
  }
  #pragma unroll
  for (int nj = 0; nj < 2; ++nj) {
    int r = wn * 32 + nj * 16 + (lane & 15);
    #pragma unroll
    for (int kh = 0; kh < 2; ++kh) {
      int ccl = kh * 4 + (lane >> 4);
      offB[nj][kh] = BM * BK + r * 64 + ((ccl ^ (r & 7)) * 8);
    }
  }

  f32x4 acc[4][2];
  #pragma unroll
  for (int mi = 0; mi < 4; ++mi)
    #pragma unroll
    for (int nj = 0; nj < 2; ++nj) acc[mi][nj] = (f32x4){0.f, 0.f, 0.f, 0.f};

  auto STAGE = [&](int sn, unsigned short* buf) {
    const long boff = (long)sn * (NPAD * 64);
    if (IMPLICIT) {
      int kkn = sn >> 2;
      int q3  = kkn / 3;
      int dy = q3 - 1, dx = kkn - q3 * 3 - 1;
      const long aoff = (long)(sn & 3) * (MTOT * 64) + (long)(dy * 64 + dx) * 64;
      #pragma unroll
      for (int i = 0; i < 2; ++i) {
        const unsigned short* src = ((vmaskA[i] >> kkn) & 1u) ? baseA[i] + aoff : zsrcA[i];
        gload16(src, buf + (i * 8 + w) * 512);
      }
    } else {
      const long aoff = (long)sn * (MTOT * 64);
      #pragma unroll
      for (int i = 0; i < 2; ++i)
        gload16(baseA[i] + aoff, buf + (i * 8 + w) * 512);
    }
    #pragma unroll
    for (int j = 0; j < 2; ++j)
      gload16(baseB[j] + boff, buf + BM * BK + (j * 8 + w) * 512);
  };

  STAGE(0, lds[0]);

  for (int s = 0; s < NSTEP; ++s) {
    if (s + 1 < NSTEP) {
      STAGE(s + 1, lds[(s + 1) & 1]);
      asm volatile("s_waitcnt vmcnt(4)" ::: "memory");
    } else {
      asm volatile("s_waitcnt vmcnt(0)" ::: "memory");
    }
    __builtin_amdgcn_s_barrier();
    __builtin_amdgcn_sched_barrier(0);

    const unsigned short* cb = lds[s & 1];
    bf16x8 af[4][2], bfg[2][2];
    #pragma unroll
    for (int mi = 0; mi < 4; ++mi)
      #pragma unroll
      for (int kh = 0; kh < 2; ++kh)
        af[mi][kh] = *(const bf16x8*)&cb[offA[mi][kh]];
    #pragma unroll
    for (int nj = 0; nj < 2; ++nj)
      #pragma unroll
      for (int kh = 0; kh < 2; ++kh)
        bfg[nj][kh] = *(const bf16x8*)&cb[offB[nj][kh]];

    #pragma unroll
    for (int kh = 0; kh < 2; ++kh)
      #pragma unroll
      for (int mi = 0; mi < 4; ++mi)
        #pragma unroll
        for (int nj = 0; nj < 2; ++nj)
          acc[mi][nj] = __builtin_amdgcn_mfma_f32_16x16x32_bf16(af[mi][kh], bfg[nj][kh],
                                                                acc[mi][nj], 0, 0, 0);
    __builtin_amdgcn_sched_barrier(0);
    asm volatile("s_waitcnt lgkmcnt(0)" ::: "memory");
    __builtin_amdgcn_s_barrier();
  }

  const int gmBase = m0 + wm * 64 + (lane >> 4) * 4;
  const int gnBase = n0 + wn * 32 + (lane & 15);
  #pragma unroll
  for (int nj = 0; nj < 2; ++nj) {
    const int gn = gnBase + nj * 16;
    const float bv = (gn < Nvalid) ? bias[gn] : 0.f;
    #pragma unroll
    for (int mi = 0; mi < 4; ++mi) {
      #pragma unroll
      for (int r = 0; r < 4; ++r) {
        const int gm = gmBase + mi * 16 + r;
        float v = acc[mi][nj][r] + bv;
        if (EPI == 0) {
          float sv = v / (1.0f + __expf(-v));
          ((unsigned short*)outp)[((size_t)(gn >> 6) * MTOT + gm) * 64 + (gn & 63)] = f2bf(sv);
        } else {
          if (gn < Nvalid) ((float*)outp)[(size_t)gm * 432 + gn] = v;
        }
      }
    }
  }
}

// ========== Fused sampler + deform GEMM ==========
// out[gm][gn] = sum_k S[gm][k] * Wd[gn][k], with S-tiles sampled on the fly into LDS.
// 512 threads: thread t samples (m = t>>2, g = 4*(sn&3)+(t&3)) each K-step; B via gload16.
__global__ __launch_bounds__(512, 1) void deform_fused_kernel(
    const float* __restrict__ t3,          // [m][432] f32
    const unsigned short* __restrict__ xh, // [c4][m][64] bf16
    const unsigned short* __restrict__ W,  // [sn][256][64] bf16
    const float* __restrict__ bias,
    float* __restrict__ out) {
  constexpr int BM = 128, BN = 128, BK = 64;
  constexpr int NSTEP = 36;
  __shared__ unsigned short ldsA[2][BM * BK];   // 2 x 16 KB
  __shared__ unsigned short ldsB[2][BN * BK];   // 2 x 16 KB

  const int t = threadIdx.x, lane = t & 63, w = t >> 6;
  const int wm = w >> 2, wn = w & 3;
  const int m0 = blockIdx.x * BM, n0 = blockIdx.y * BN;

  // ---- sampling identity: one sample per thread per step ----
  const int mr = t >> 2, q = t & 3;
  const int gms = m0 + mr;
  const int bs = gms >> 12, pix = gms & 4095;
  const int ysi = pix >> 6, xsi = pix & 63;
  const float* offp = t3 + (size_t)gms * 432;
  // LDS A write offsets: logical chunks 2q, 2q+1 of row mr, XOR-swizzled (matches read side)
  const int wofA0 = mr * 64 + (((2 * q)     ^ (mr & 7)) * 8);
  const int wofA1 = mr * 64 + (((2 * q + 1) ^ (mr & 7)) * 8);

  // ---- B staging descriptors ----
  const unsigned short* baseB[2];
  int wofB[2];
  #pragma unroll
  for (int j = 0; j < 2; ++j) {
    int c   = (j * 8 + w) * 64 + lane;
    int row = c >> 3;
    int ccl = (c & 7) ^ (row & 7);
    baseB[j] = W + (size_t)(n0 + row) * 64 + ccl * 8;
    wofB[j]  = (j * 8 + w) * 512;
  }

  // ---- fragment read offsets ----
  int offA[4][2], offB[2][2];
  #pragma unroll
  for (int mi = 0; mi < 4; ++mi) {
    int r = wm * 64 + mi * 16 + (lane & 15);
    #pragma unroll
    for (int kh = 0; kh < 2; ++kh) {
      int ccl = kh * 4 + (lane >> 4);
      offA[mi][kh] = r * 64 + ((ccl ^ (r & 7)) * 8);
    }
  }
  #pragma unroll
  for (int nj = 0; nj < 2; ++nj) {
    int r = wn * 32 + nj * 16 + (lane & 15);
    #pragma unroll
    for (int kh = 0; kh < 2; ++kh) {
      int ccl = kh * 4 + (lane >> 4);
      offB[nj][kh] = r * 64 + ((ccl ^ (r & 7)) * 8);
    }
  }

  f32x4 acc[4][2];
  #pragma unroll
  for (int mi = 0; mi < 4; ++mi)
    #pragma unroll
    for (int nj = 0; nj < 2; ++nj) acc[mi][nj] = (f32x4){0.f, 0.f, 0.f, 0.f};

  auto T_LOAD = [&](int sn, float& dyv, float& dxv, float& ml) {
    int kk = sn >> 2;
    int g  = ((sn & 3) << 2) + q;
    int base = g * 9 + kk;
    dyv = offp[2 * base];
    dxv = offp[2 * base + 1];
    ml  = offp[288 + base];
  };

  // computes weights + issues the 8 corner gathers
  auto GATHER = [&](int sn, float dyv, float dxv, float ml, u16x8* cr, f32x4& wg) {
    int kk = sn >> 2;
    int ki = kk / 3, kj = kk - 3 * (kk / 3);
    float mk = 1.0f / (1.0f + __expf(-ml));
    float ysf = (float)(ysi - 1 + ki) + dyv;
    float xsf = (float)(xsi - 1 + kj) + dxv;
    float y0f = floorf(ysf), x0f = floorf(xsf);
    float wy = ysf - y0f, wx = xsf - x0f;
    int yi0 = (int)y0f, xi0 = (int)x0f;
    int yi1 = yi0 + 1, xi1 = xi0 + 1;
    bool vy0 = (yi0 >= 0) && (yi0 < 64), vy1 = (yi1 >= 0) && (yi1 < 64);
    bool vx0 = (xi0 >= 0) && (xi0 < 64), vx1 = (xi1 >= 0) && (xi1 < 64);
    int yc0 = min(max(yi0, 0), 63), yc1 = min(max(yi1, 0), 63);
    int xc0 = min(max(xi0, 0), 63), xc1 = min(max(xi1, 0), 63);
    wg[0] = (vy0 && vx0) ? (1.f - wy) * (1.f - wx) * mk : 0.f;
    wg[1] = (vy0 && vx1) ? (1.f - wy) * wx * mk : 0.f;
    wg[2] = (vy1 && vx0) ? wy * (1.f - wx) * mk : 0.f;
    wg[3] = (vy1 && vx1) ? wy * wx * mk : 0.f;
    const unsigned short* gb = xh + ((size_t)(sn & 3) * MTOT + ((size_t)bs << 12)) * 64 + q * 16;
    const int p00 = yc0 * 64 + xc0, p01 = yc0 * 64 + xc1;
    const int p10 = yc1 * 64 + xc0, p11 = yc1 * 64 + xc1;
    cr[0] = *(const u16x8*)(gb + (size_t)p00 * 64);
    cr[1] = *(const u16x8*)(gb + (size_t)p00 * 64 + 8);
    cr[2] = *(const u16x8*)(gb + (size_t)p01 * 64);
    cr[3] = *(const u16x8*)(gb + (size_t)p01 * 64 + 8);
    cr[4] = *(const u16x8*)(gb + (size_t)p10 * 64);
    cr[5] = *(const u16x8*)(gb + (size_t)p10 * 64 + 8);
    cr[6] = *(const u16x8*)(gb + (size_t)p11 * 64);
    cr[7] = *(const u16x8*)(gb + (size_t)p11 * 64 + 8);
  };

  auto COMBINE_WRITE = [&](const u16x8* cr, f32x4 wg, unsigned short* bufA) {
    u16x8 olo, ohi;
    #pragma unroll
    for (int j = 0; j < 8; ++j) {
      float sl = wg[0] * b2f(cr[0][j]) + wg[1] * b2f(cr[2][j])
               + wg[2] * b2f(cr[4][j]) + wg[3] * b2f(cr[6][j]);
      float sh = wg[0] * b2f(cr[1][j]) + wg[1] * b2f(cr[3][j])
               + wg[2] * b2f(cr[5][j]) + wg[3] * b2f(cr[7][j]);
      olo[j] = f2bf(sl);
      ohi[j] = f2bf(sh);
    }
    *(u16x8*)&bufA[wofA0] = olo;
    *(u16x8*)&bufA[wofA1] = ohi;
  };

  // ---- prologue: sample step 0, stage B(0) ----
  {
    float dy0, dx0, ml0;
    T_LOAD(0, dy0, dx0, ml0);
    u16x8 cr[8]; f32x4 wg;
    GATHER(0, dy0, dx0, ml0, cr, wg);
    COMBINE_WRITE(cr, wg, ldsA[0]);
    #pragma unroll
    for (int j = 0; j < 2; ++j)
      gload16(baseB[j], ldsB[0] + wofB[j]);
  }
  __syncthreads();

  float dyN, dxN, mlN;
  T_LOAD(1, dyN, dxN, mlN);

  for (int s = 0; s < NSTEP; ++s) {
    const int sn = s + 1;
    u16x8 cr[8]; f32x4 wg;
    if (sn < NSTEP) {
      #pragma unroll
      for (int j = 0; j < 2; ++j)
        gload16(baseB[j] + (size_t)sn * (256 * 64), ldsB[sn & 1] + wofB[j]);
      GATHER(sn, dyN, dxN, mlN, cr, wg);      // issues 8 gathers; consumed after MFMA
    }
    float dy2 = 0.f, dx2 = 0.f, ml2 = 0.f;
    if (s + 2 < NSTEP) T_LOAD(s + 2, dy2, dx2, ml2);

    const unsigned short* cA = ldsA[s & 1];
    const unsigned short* cB = ldsB[s & 1];
    bf16x8 af[4][2], bfg[2][2];
    #pragma unroll
    for (int mi = 0; mi < 4; ++mi)
      #pragma unroll
      for (int kh = 0; kh < 2; ++kh)
        af[mi][kh] = *(const bf16x8*)&cA[offA[mi][kh]];
    #pragma unroll
    for (int nj = 0; nj < 2; ++nj)
      #pragma unroll
      for (int kh = 0; kh < 2; ++kh)
        bfg[nj][kh] = *(const bf16x8*)&cB[offB[nj][kh]];

    #pragma unroll
    for (int kh = 0; kh < 2; ++kh)
      #pragma unroll
      for (int mi = 0; mi < 4; ++mi)
        #pragma unroll
        for (int nj = 0; nj < 2; ++nj)
          acc[mi][nj] = __builtin_amdgcn_mfma_f32_16x16x32_bf16(af[mi][kh], bfg[nj][kh],
                                                                acc[mi][nj], 0, 0, 0);

    if (sn < NSTEP) COMBINE_WRITE(cr, wg, ldsA[sn & 1]);
    dyN = dy2; dxN = dx2; mlN = ml2;
    __syncthreads();   // drains vm+lgkm: next step's A (ds_write) and B (gload) both ready
  }

  // epilogue: f32 NCHW out + bias
  const int gmBase = m0 + wm * 64 + (lane >> 4) * 4;
  const int gnBase = n0 + wn * 32 + (lane & 15);
  #pragma unroll
  for (int nj = 0; nj < 2; ++nj) {
    const int gn = gnBase + nj * 16;
    const float bv = bias[gn];
    #pragma unroll
    for (int mi = 0; mi < 4; ++mi) {
      #pragma unroll
      for (int r = 0; r < 4; ++r) {
        const int gm = gmBase + mi * 16 + r;
        out[((size_t)(gm >> 12) * 256 + gn) * 4096 + (gm & 4095)] = acc[mi][nj][r] + bv;
      }
    }
  }
}

extern "C" void kernel_launch(void* const* d_in, const int* in_sizes, int n_in,
                              void* d_out, int out_size, void* d_ws, size_t ws_size,
                              hipStream_t stream) {
  const float* x      = (const float*)d_in[0];
  const float* offeat = (const float*)d_in[1];
  const float* weight = (const float*)d_in[2];
  const float* bias   = (const float*)d_in[3];
  const float* w1     = (const float*)d_in[4];
  const float* b1     = (const float*)d_in[5];
  const float* w2     = (const float*)d_in[6];
  const float* b2     = (const float*)d_in[7];
  const float* w3     = (const float*)d_in[8];
  const float* b3     = (const float*)d_in[9];
  float* out = (float*)d_out;

  char* ws = (char*)d_ws;
  unsigned short* xh  = (unsigned short*)(ws + 0);            //  8,388,608 B (4 planes)
  float*          t3  = (float*)(ws + 8388608);               // 28,311,552 B
  unsigned short* Wd  = (unsigned short*)(ws + 36700160);     //  1,179,648 B
  unsigned short* zb  = (unsigned short*)(ws + 37879808);     //        256 B
  unsigned short* fh  = (unsigned short*)(ws + 37880064);     //  8,388,608 B
  unsigned short* t1  = (unsigned short*)(ws + 46268672);     //  8,388,608 B
  unsigned short* t2  = (unsigned short*)(ws + 54657280);     //  8,388,608 B
  unsigned short* W1p = (unsigned short*)(ws + 63045888);     //  1,179,648 B
  unsigned short* W2p = (unsigned short*)(ws + 64225536);     //  1,179,648 B
  unsigned short* W3p = (unsigned short*)(ws + 65405184);     //  2,359,296 B (NPAD 512)

  hipMemsetAsync(zb, 0, 256, stream);

  // layout conversions
  nhwc_kernel<<<dim3(64, 4), 256, 0, stream>>>(x, xh);
  nhwc_kernel<<<dim3(64, 4), 256, 0, stream>>>(offeat, fh);
  wprep_kernel<<<dim3(36, 64), 256, 0, stream>>>(w1, W1p, 256, 256);
  wprep_kernel<<<dim3(36, 64), 256, 0, stream>>>(w2, W2p, 256, 256);
  wprep_kernel<<<dim3(36, 128), 256, 0, stream>>>(w3, W3p, 512, 432);
  wprep_kernel<<<dim3(36, 64), 256, 0, stream>>>(weight, Wd, 256, 256);

  // conv1 (silu) -> t1, conv2 (silu) -> t2  [8-wave]
  gemm8_kernel<256, 0, true><<<dim3(128, 2), 512, 0, stream>>>(fh, W1p, b1, t1, zb, 256);
  gemm8_kernel<256, 0, true><<<dim3(128, 2), 512, 0, stream>>>(t1, W2p, b2, t2, zb, 256);

  // conv3 -> t3 (f32 + bias)  [8-wave, 2 blocks/CU]
  gemm8_kernel<512, 1, true><<<dim3(128, 4), 512, 0, stream>>>(t2, W3p, b3, t3, zb, 432);

  // fused bilinear-sample + deform GEMM -> out (f32 NCHW)
  deform_fused_kernel<<<dim3(128, 2), 512, 0, stream>>>(t3, xh, Wd, bias, out);
}

// Round 16
// 203.134 us; speedup vs baseline: 1.0955x; 1.0955x over previous
//
#include <hip/hip_runtime.h>
#include <math.h>

typedef __attribute__((ext_vector_type(8))) short  bf16x8;
typedef __attribute__((ext_vector_type(8))) unsigned short u16x8;
typedef __attribute__((ext_vector_type(4))) float  f32x4;

#define MTOT 16384   // B*H*W

__device__ __forceinline__ float b2f(unsigned short h) {
  return __uint_as_float(((unsigned int)h) << 16);
}
__device__ __forceinline__ unsigned short f2bf(float f) {
  unsigned int u = __float_as_uint(f);
  unsigned int r = (u + 0x7fffu + ((u >> 16) & 1u)) >> 16;
  return (unsigned short)r;
}
__device__ __forceinline__ void gload16(const unsigned short* g, unsigned short* l) {
  __builtin_amdgcn_global_load_lds(
      (const __attribute__((address_space(1))) void*)g,
      (__attribute__((address_space(3))) void*)l, 16, 0, 0);
}

// ------- NCHW fp32 -> chunked bf16 planes  out[c4][m][64] -------
__global__ __launch_bounds__(256) void nhwc_kernel(const float* __restrict__ in,
                                                   unsigned short* __restrict__ out) {
  const int y = blockIdx.x, b = blockIdx.y;
  const int t = threadIdx.x;
  __shared__ float lds[64 * 65];
  for (int c0 = 0; c0 < 256; c0 += 64) {
    #pragma unroll
    for (int i = 0; i < 16; ++i) {
      int cl = i * 4 + (t >> 6);
      int xx = t & 63;
      lds[cl * 65 + xx] = in[(((size_t)b * 256 + c0 + cl) * 64 + y) * 64 + xx];
    }
    __syncthreads();
    const int plane = c0 >> 6;
    #pragma unroll
    for (int i = 0; i < 16; ++i) {
      int xx = i * 4 + (t >> 6);
      int cl = t & 63;
      int m  = (b << 12) + (y << 6) + xx;
      out[((size_t)plane * MTOT + m) * 64 + cl] = f2bf(lds[cl * 65 + xx]);
    }
    __syncthreads();
  }
}

// ------- weight reorder: w[co][ci][kk] fp32 -> Wp[(kk*4+c4)*NPAD + co][64ci] bf16 -------
__global__ __launch_bounds__(256) void wprep_kernel(const float* __restrict__ w,
                                                    unsigned short* __restrict__ Wp,
                                                    int NPAD, int COUT_valid) {
  const int kkc4 = blockIdx.x;
  const int kk = kkc4 >> 2, c4 = kkc4 & 3;
  const int co = blockIdx.y * 4 + (threadIdx.x >> 6);
  const int c16 = threadIdx.x & 63;
  float v = (co < COUT_valid) ? w[((size_t)co * 256 + c4 * 64 + c16) * 9 + kk] : 0.0f;
  Wp[((size_t)kkc4 * NPAD + co) * 64 + c16] = f2bf(v);
}

// ------- sampler v2: 2 threads per sample (8-ch halves), grid 2048 -> 32 waves/CU -------
__global__ __launch_bounds__(256) void sampler_kernel(const float* __restrict__ t3,
                                                      const unsigned short* __restrict__ xh,
                                                      unsigned short* __restrict__ S) {
  const int t = threadIdx.x;
  const int h = t & 1;               // 8-channel half
  const int g = (t >> 1) & 15;
  const int m = blockIdx.x * 8 + (t >> 5);
  const int b = m >> 12, pix = m & 4095, y = pix >> 6, x = pix & 63;
  const float* off = t3 + (size_t)m * 432;
  const size_t gbase = ((size_t)(g >> 2) * MTOT + ((size_t)b << 12)) * 64 + (g & 3) * 16 + h * 8;

  #pragma unroll
  for (int kk = 0; kk < 9; ++kk) {
    const int ki = kk / 3, kj = kk % 3;
    float dyv = off[2 * (g * 9 + kk)];
    float dxv = off[2 * (g * 9 + kk) + 1];
    float ml  = off[288 + g * 9 + kk];
    float mk  = 1.0f / (1.0f + __expf(-ml));
    float ysf = (float)(y - 1 + ki) + dyv;
    float xsf = (float)(x - 1 + kj) + dxv;
    float y0f = floorf(ysf), x0f = floorf(xsf);
    float wy = ysf - y0f, wx = xsf - x0f;
    int yi0 = (int)y0f, xi0 = (int)x0f;
    int yi1 = yi0 + 1, xi1 = xi0 + 1;
    bool vy0 = (yi0 >= 0) && (yi0 < 64), vy1 = (yi1 >= 0) && (yi1 < 64);
    bool vx0 = (xi0 >= 0) && (xi0 < 64), vx1 = (xi1 >= 0) && (xi1 < 64);
    int yc0 = min(max(yi0, 0), 63), yc1 = min(max(yi1, 0), 63);
    int xc0 = min(max(xi0, 0), 63), xc1 = min(max(xi1, 0), 63);
    float w00 = (vy0 && vx0) ? (1.f - wy) * (1.f - wx) * mk : 0.f;
    float w01 = (vy0 && vx1) ? (1.f - wy) * wx * mk : 0.f;
    float w10 = (vy1 && vx0) ? wy * (1.f - wx) * mk : 0.f;
    float w11 = (vy1 && vx1) ? wy * wx * mk : 0.f;

    const int p00 = yc0 * 64 + xc0, p01 = yc0 * 64 + xc1;
    const int p10 = yc1 * 64 + xc0, p11 = yc1 * 64 + xc1;
    u16x8 c00 = *(const u16x8*)(xh + gbase + (size_t)p00 * 64);
    u16x8 c01 = *(const u16x8*)(xh + gbase + (size_t)p01 * 64);
    u16x8 c10 = *(const u16x8*)(xh + gbase + (size_t)p10 * 64);
    u16x8 c11 = *(const u16x8*)(xh + gbase + (size_t)p11 * 64);
    u16x8 o;
    #pragma unroll
    for (int j = 0; j < 8; ++j) {
      float s = w00 * b2f(c00[j]) + w01 * b2f(c01[j]) + w10 * b2f(c10[j]) + w11 * b2f(c11[j]);
      o[j] = f2bf(s);
    }
    *(u16x8*)(S + ((size_t)(kk * 4 + (g >> 2)) * MTOT + m) * 64 + (g & 3) * 16 + h * 8) = o;
  }
}

// ========== Config A (R14 proven): 8-wave, 128x128 tile, wave 64x32, 1 blk/CU ==========
__global__ __launch_bounds__(512, 1) void convA_kernel(
    const unsigned short* __restrict__ A,
    const unsigned short* __restrict__ W,
    const float* __restrict__ bias,
    unsigned short* __restrict__ outp,
    const unsigned short* __restrict__ zbuf) {
  constexpr int BM = 128, BN = 128, BK = 64, NSTEP = 36, NPAD = 256;
  __shared__ unsigned short lds[2][(BM + BN) * BK];

  const int t = threadIdx.x, lane = t & 63, w = t >> 6;
  const int wm = w >> 2, wn = w & 3;
  const int m0 = blockIdx.x * BM, n0 = blockIdx.y * BN;

  const unsigned short* baseA[2];
  const unsigned short* zsrcA[2];
  unsigned int vmaskA[2];
  #pragma unroll
  for (int i = 0; i < 2; ++i) {
    int c   = (i * 8 + w) * 64 + lane;
    int row = c >> 3;
    int ccl = (c & 7) ^ (row & 7);
    int m   = m0 + row;
    baseA[i] = A + (size_t)m * 64 + ccl * 8;
    zsrcA[i] = zbuf + ccl * 8;
    int y = (m >> 6) & 63, x = m & 63;
    unsigned int vm = 0;
    #pragma unroll
    for (int kk = 0; kk < 9; ++kk) {
      int dy = kk / 3 - 1, dx = kk % 3 - 1;
      if ((unsigned)(y + dy) < 64u && (unsigned)(x + dx) < 64u) vm |= (1u << kk);
    }
    vmaskA[i] = vm;
  }
  const unsigned short* baseB[2];
  #pragma unroll
  for (int j = 0; j < 2; ++j) {
    int c   = (j * 8 + w) * 64 + lane;
    int row = c >> 3;
    int ccl = (c & 7) ^ (row & 7);
    baseB[j] = W + (size_t)(n0 + row) * 64 + ccl * 8;
  }

  int offA[4][2], offB[2][2];
  #pragma unroll
  for (int mi = 0; mi < 4; ++mi) {
    int r = wm * 64 + mi * 16 + (lane & 15);
    #pragma unroll
    for (int kh = 0; kh < 2; ++kh)
      offA[mi][kh] = r * 64 + (((kh * 4 + (lane >> 4)) ^ (r & 7)) * 8);
  }
  #pragma unroll
  for (int nj = 0; nj < 2; ++nj) {
    int r = wn * 32 + nj * 16 + (lane & 15);
    #pragma unroll
    for (int kh = 0; kh < 2; ++kh)
      offB[nj][kh] = BM * BK + r * 64 + (((kh * 4 + (lane >> 4)) ^ (r & 7)) * 8);
  }

  f32x4 acc[4][2];
  #pragma unroll
  for (int mi = 0; mi < 4; ++mi)
    #pragma unroll
    for (int nj = 0; nj < 2; ++nj) acc[mi][nj] = (f32x4){0.f, 0.f, 0.f, 0.f};

  auto STAGE = [&](int sn, unsigned short* buf) {
    int kkn = sn >> 2;
    int q3  = kkn / 3;
    const long aoff = (long)(sn & 3) * (MTOT * 64) + (long)((q3 - 1) * 64 + (kkn - q3 * 3 - 1)) * 64;
    const long boff = (long)sn * (NPAD * 64);
    #pragma unroll
    for (int i = 0; i < 2; ++i) {
      const unsigned short* src = ((vmaskA[i] >> kkn) & 1u) ? baseA[i] + aoff : zsrcA[i];
      gload16(src, buf + (i * 8 + w) * 512);
    }
    #pragma unroll
    for (int j = 0; j < 2; ++j)
      gload16(baseB[j] + boff, buf + BM * BK + (j * 8 + w) * 512);
  };

  STAGE(0, lds[0]);

  for (int s = 0; s < NSTEP; ++s) {
    if (s + 1 < NSTEP) {
      STAGE(s + 1, lds[(s + 1) & 1]);
      asm volatile("s_waitcnt vmcnt(4)" ::: "memory");
    } else {
      asm volatile("s_waitcnt vmcnt(0)" ::: "memory");
    }
    __builtin_amdgcn_s_barrier();
    __builtin_amdgcn_sched_barrier(0);

    const unsigned short* cb = lds[s & 1];
    bf16x8 af[4][2], bfg[2][2];
    #pragma unroll
    for (int mi = 0; mi < 4; ++mi)
      #pragma unroll
      for (int kh = 0; kh < 2; ++kh)
        af[mi][kh] = *(const bf16x8*)&cb[offA[mi][kh]];
    #pragma unroll
    for (int nj = 0; nj < 2; ++nj)
      #pragma unroll
      for (int kh = 0; kh < 2; ++kh)
        bfg[nj][kh] = *(const bf16x8*)&cb[offB[nj][kh]];

    #pragma unroll
    for (int kh = 0; kh < 2; ++kh)
      #pragma unroll
      for (int mi = 0; mi < 4; ++mi)
        #pragma unroll
        for (int nj = 0; nj < 2; ++nj)
          acc[mi][nj] = __builtin_amdgcn_mfma_f32_16x16x32_bf16(af[mi][kh], bfg[nj][kh],
                                                                acc[mi][nj], 0, 0, 0);
    __builtin_amdgcn_sched_barrier(0);
    asm volatile("s_waitcnt lgkmcnt(0)" ::: "memory");
    __builtin_amdgcn_s_barrier();
  }

  const int gmBase = m0 + wm * 64 + (lane >> 4) * 4;
  const int gnBase = n0 + wn * 32 + (lane & 15);
  #pragma unroll
  for (int nj = 0; nj < 2; ++nj) {
    const int gn = gnBase + nj * 16;
    const float bv = bias[gn];
    #pragma unroll
    for (int mi = 0; mi < 4; ++mi) {
      #pragma unroll
      for (int r = 0; r < 4; ++r) {
        const int gm = gmBase + mi * 16 + r;
        float v = acc[mi][nj][r] + bv;
        float sv = v / (1.0f + __expf(-v));
        outp[((size_t)(gn >> 6) * MTOT + gm) * 64 + (gn & 63)] = f2bf(sv);
      }
    }
  }
}

// ========== Config B: 8-wave, 128x64 tile, wave 32x32, 48KB LDS -> 2-3 blk/CU ==========
// EPI: 0 = silu -> bf16 planes; 1 = f32 [m][432]+bias (guard); 2 = f32 NCHW.
template<int NPAD, int EPI, bool IMPLICIT>
__global__ __launch_bounds__(512, 4) void gemmB_kernel(
    const unsigned short* __restrict__ A,
    const unsigned short* __restrict__ W,
    const float* __restrict__ bias,
    void* __restrict__ outp,
    const unsigned short* __restrict__ zbuf,
    int Nvalid) {
  constexpr int BM = 128, BN = 64, BK = 64, NSTEP = 36;
  __shared__ unsigned short lds[2][(BM + BN) * BK];   // 2 x 24 KB

  const int t = threadIdx.x, lane = t & 63, w = t >> 6;
  const int wm = w >> 1, wn = w & 1;                   // 4m x 2n waves, tile 32x32
  const int m0 = blockIdx.x * BM, n0 = blockIdx.y * BN;

  // A staging: chunks c = i*8+w (i=0..1), rows 8c..8c+7
  const unsigned short* baseA[2];
  const unsigned short* zsrcA[2];
  unsigned int vmaskA[2];
  #pragma unroll
  for (int i = 0; i < 2; ++i) {
    int c   = (i * 8 + w) * 64 + lane;
    int row = c >> 3;
    int ccl = (c & 7) ^ (row & 7);
    int m   = m0 + row;
    baseA[i] = A + (size_t)m * 64 + ccl * 8;
    zsrcA[i] = zbuf + ccl * 8;
    if (IMPLICIT) {
      int y = (m >> 6) & 63, x = m & 63;
      unsigned int vm = 0;
      #pragma unroll
      for (int kk = 0; kk < 9; ++kk) {
        int dy = kk / 3 - 1, dx = kk % 3 - 1;
        if ((unsigned)(y + dy) < 64u && (unsigned)(x + dx) < 64u) vm |= (1u << kk);
      }
      vmaskA[i] = vm;
    } else {
      vmaskA[i] = 0;
    }
  }
  // B staging: chunk c = w (rows 8w..8w+7)
  const unsigned short* baseB;
  {
    int c   = w * 64 + lane;
    int row = c >> 3;
    int ccl = (c & 7) ^ (row & 7);
    baseB = W + (size_t)(n0 + row) * 64 + ccl * 8;
  }

  int offA[2][2], offB[2][2];
  #pragma unroll
  for (int mi = 0; mi < 2; ++mi) {
    int r = wm * 32 + mi * 16 + (lane & 15);
    #pragma unroll
    for (int kh = 0; kh < 2; ++kh)
      offA[mi][kh] = r * 64 + (((kh * 4 + (lane >> 4)) ^ (r & 7)) * 8);
  }
  #pragma unroll
  for (int nj = 0; nj < 2; ++nj) {
    int r = wn * 32 + nj * 16 + (lane & 15);
    #pragma unroll
    for (int kh = 0; kh < 2; ++kh)
      offB[nj][kh] = BM * BK + r * 64 + (((kh * 4 + (lane >> 4)) ^ (r & 7)) * 8);
  }

  f32x4 acc[2][2];
  #pragma unroll
  for (int mi = 0; mi < 2; ++mi)
    #pragma unroll
    for (int nj = 0; nj < 2; ++nj) acc[mi][nj] = (f32x4){0.f, 0.f, 0.f, 0.f};

  auto STAGE = [&](int sn, unsigned short* buf) {
    const long boff = (long)sn * (NPAD * 64);
    if (IMPLICIT) {
      int kkn = sn >> 2;
      int q3  = kkn / 3;
      const long aoff = (long)(sn & 3) * (MTOT * 64) + (long)((q3 - 1) * 64 + (kkn - q3 * 3 - 1)) * 64;
      #pragma unroll
      for (int i = 0; i < 2; ++i) {
        const unsigned short* src = ((vmaskA[i] >> kkn) & 1u) ? baseA[i] + aoff : zsrcA[i];
        gload16(src, buf + (i * 8 + w) * 512);
      }
    } else {
      const long aoff = (long)sn * (MTOT * 64);
      #pragma unroll
      for (int i = 0; i < 2; ++i)
        gload16(baseA[i] + aoff, buf + (i * 8 + w) * 512);
    }
    gload16(baseB + boff, buf + BM * BK + w * 512);
  };

  STAGE(0, lds[0]);

  for (int s = 0; s < NSTEP; ++s) {
    if (s + 1 < NSTEP) {
      STAGE(s + 1, lds[(s + 1) & 1]);
      asm volatile("s_waitcnt vmcnt(3)" ::: "memory");
    } else {
      asm volatile("s_waitcnt vmcnt(0)" ::: "memory");
    }
    __builtin_amdgcn_s_barrier();
    __builtin_amdgcn_sched_barrier(0);

    const unsigned short* cb = lds[s & 1];
    bf16x8 af[2][2], bfg[2][2];
    #pragma unroll
    for (int mi = 0; mi < 2; ++mi)
      #pragma unroll
      for (int kh = 0; kh < 2; ++kh)
        af[mi][kh] = *(const bf16x8*)&cb[offA[mi][kh]];
    #pragma unroll
    for (int nj = 0; nj < 2; ++nj)
      #pragma unroll
      for (int kh = 0; kh < 2; ++kh)
        bfg[nj][kh] = *(const bf16x8*)&cb[offB[nj][kh]];

    #pragma unroll
    for (int kh = 0; kh < 2; ++kh)
      #pragma unroll
      for (int mi = 0; mi < 2; ++mi)
        #pragma unroll
        for (int nj = 0; nj < 2; ++nj)
          acc[mi][nj] = __builtin_amdgcn_mfma_f32_16x16x32_bf16(af[mi][kh], bfg[nj][kh],
                                                                acc[mi][nj], 0, 0, 0);
    __builtin_amdgcn_sched_barrier(0);
    asm volatile("s_waitcnt lgkmcnt(0)" ::: "memory");
    __builtin_amdgcn_s_barrier();
  }

  const int gmBase = m0 + wm * 32 + (lane >> 4) * 4;
  const int gnBase = n0 + wn * 32 + (lane & 15);
  #pragma unroll
  for (int nj = 0; nj < 2; ++nj) {
    const int gn = gnBase + nj * 16;
    const float bv = (gn < Nvalid) ? bias[gn] : 0.f;
    #pragma unroll
    for (int mi = 0; mi < 2; ++mi) {
      #pragma unroll
      for (int r = 0; r < 4; ++r) {
        const int gm = gmBase + mi * 16 + r;
        float v = acc[mi][nj][r] + bv;
        if (EPI == 0) {
          float sv = v / (1.0f + __expf(-v));
          ((unsigned short*)outp)[((size_t)(gn >> 6) * MTOT + gm) * 64 + (gn & 63)] = f2bf(sv);
        } else if (EPI == 1) {
          if (gn < Nvalid) ((float*)outp)[(size_t)gm * 432 + gn] = v;
        } else {
          ((float*)outp)[((size_t)(gm >> 12) * 256 + gn) * 4096 + (gm & 4095)] = v;
        }
      }
    }
  }
}

extern "C" void kernel_launch(void* const* d_in, const int* in_sizes, int n_in,
                              void* d_out, int out_size, void* d_ws, size_t ws_size,
                              hipStream_t stream) {
  const float* x      = (const float*)d_in[0];
  const float* offeat = (const float*)d_in[1];
  const float* weight = (const float*)d_in[2];
  const float* bias   = (const float*)d_in[3];
  const float* w1     = (const float*)d_in[4];
  const float* b1     = (const float*)d_in[5];
  const float* w2     = (const float*)d_in[6];
  const float* b2     = (const float*)d_in[7];
  const float* w3     = (const float*)d_in[8];
  const float* b3     = (const float*)d_in[9];
  float* out = (float*)d_out;

  char* ws = (char*)d_ws;
  unsigned short* xh  = (unsigned short*)(ws + 0);            //  8,388,608 B (4 planes)
  float*          t3  = (float*)(ws + 8388608);               // 28,311,552 B
  unsigned short* Wd  = (unsigned short*)(ws + 36700160);     //  1,179,648 B
  unsigned short* zb  = (unsigned short*)(ws + 37879808);     //        256 B
  unsigned short* S   = (unsigned short*)(ws + 37880064);     // 75,497,472 B (36 planes)
  // overlay region inside S's span (dead before sampler writes S)
  unsigned short* fh  = (unsigned short*)(ws + 37880064);     //  8,388,608 B
  unsigned short* t1  = (unsigned short*)(ws + 46268672);     //  8,388,608 B
  unsigned short* t2  = (unsigned short*)(ws + 54657280);     //  8,388,608 B
  unsigned short* W1p = (unsigned short*)(ws + 63045888);     //  1,179,648 B
  unsigned short* W2p = (unsigned short*)(ws + 64225536);     //  1,179,648 B
  unsigned short* W3p = (unsigned short*)(ws + 65405184);     //  2,064,384 B (NPAD 448)

  hipMemsetAsync(zb, 0, 256, stream);

  nhwc_kernel<<<dim3(64, 4), 256, 0, stream>>>(x, xh);
  nhwc_kernel<<<dim3(64, 4), 256, 0, stream>>>(offeat, fh);
  wprep_kernel<<<dim3(36, 64), 256, 0, stream>>>(w1, W1p, 256, 256);
  wprep_kernel<<<dim3(36, 64), 256, 0, stream>>>(w2, W2p, 256, 256);
  wprep_kernel<<<dim3(36, 112), 256, 0, stream>>>(w3, W3p, 448, 432);
  wprep_kernel<<<dim3(36, 64), 256, 0, stream>>>(weight, Wd, 256, 256);

  // conv1: Config A (R14 baseline) — in-round A/B vs conv2 (identical shape)
  convA_kernel<<<dim3(128, 2), 512, 0, stream>>>(fh, W1p, b1, t1, zb);
  // conv2: Config B (2-3 blocks/CU)
  gemmB_kernel<256, 0, true><<<dim3(128, 4), 512, 0, stream>>>(t1, W2p, b2, t2, zb, 256);
  // conv3: Config B
  gemmB_kernel<448, 1, true><<<dim3(128, 7), 512, 0, stream>>>(t2, W3p, b3, t3, zb, 432);

  // sampler v2 (32 waves/CU)
  sampler_kernel<<<dim3(2048), 256, 0, stream>>>(t3, xh, S);

  // deform: Config B, explicit A from S planes
  gemmB_kernel<256, 2, false><<<dim3(128, 4), 512, 0, stream>>>(S, Wd, bias, out, zb, 256);
}